// Round 14
// baseline (2559.990 us; speedup 1.0000x reference)
//
#include <hip/hip_runtime.h>
#include <hip/hip_fp16.h>

#define NN 160
#define KP 81                // kept kz planes (Hermitian half)
#define N3 4096000           // 160^3
#define NLINES 25600         // 160^2 z-lines
#define WZ 8                 // tile width (kz columns) for y sweeps
#define NBZ 11               // ceil(81/8)
#define XW 4                 // tile width for x sweeps (128-thread blocks)
#define NBX4 21              // ceil(81/4)
#define XS 12960             // x-stride in complex layout (160*81)
#define TPI 6.28318530717958647692f
#define LAM_F 0.05f
#define SC160 (1.f/160.f)

// ---------------- complex helpers ----------------
__device__ __forceinline__ float2 cxmul(float2 a, float2 b){
    return make_float2(a.x*b.x - a.y*b.y, a.x*b.y + a.y*b.x);
}
__device__ __forceinline__ float2 cadd(float2 a, float2 b){ return make_float2(a.x+b.x, a.y+b.y); }
__device__ __forceinline__ float2 csub(float2 a, float2 b){ return make_float2(a.x-b.x, a.y-b.y); }
__device__ __forceinline__ float2 cscale(float2 a, float s){ return make_float2(a.x*s, a.y*s); }
__device__ __forceinline__ float2 shfl2(float2 v, int m){
    return make_float2(__shfl_xor(v.x, m, 64), __shfl_xor(v.y, m, 64));
}
__device__ __forceinline__ int br5(int l){
    return ((l&1)<<4)|((l&2)<<2)|(l&4)|((l&8)>>2)|((l&16)>>4);
}
__device__ __forceinline__ float2 h2f(__half2 h){ return __half22float2(h); }
__device__ __forceinline__ __half2 f2h(float2 f){ return __float22half2_rn(f); }
// rev in revolutions (angle/2pi). v_sin_f32/v_cos_f32 are revolution-input
// on gfx950 -> 1 instr each, no range reduction needed.
__device__ __forceinline__ float fsin_rev(float rev){ return __builtin_amdgcn_sinf(rev); }
__device__ __forceinline__ float fcos_rev(float rev){ return __builtin_amdgcn_cosf(rev); }
template<int SGN>
__device__ __forceinline__ float2 twid(float rev){
    float s = fsin_rev(rev), c = fcos_rev(rev);
    return make_float2(c, (SGN>0) ? -s : s);
}

// ---------------- radix-5 DFT ----------------
template<int SGN>
__device__ __forceinline__ void dft5(float2 y[5]){
    const float C1 = 0.30901699437494742f;
    const float C2 = -0.80901699437494742f;
    const float S1 = 0.95105651629515357f;
    const float S2 = 0.58778525229247312f;
    float2 x0=y[0], x1=y[1], x2=y[2], x3=y[3], x4=y[4];
    float2 t1=cadd(x1,x4), t2=cadd(x2,x3), t3=csub(x1,x4), t4=csub(x2,x3);
    y[0] = cadd(x0, cadd(t1,t2));
    float2 a1 = make_float2(x0.x + C1*t1.x + C2*t2.x, x0.y + C1*t1.y + C2*t2.y);
    float2 a2 = make_float2(x0.x + C2*t1.x + C1*t2.x, x0.y + C2*t1.y + C1*t2.y);
    const float sg = (SGN>0) ? 1.f : -1.f;
    float2 b1 = make_float2(sg*(S1*t3.x + S2*t4.x), sg*(S1*t3.y + S2*t4.y));
    float2 b2 = make_float2(sg*(S2*t3.x - S1*t4.x), sg*(S2*t3.y - S1*t4.y));
    y[1] = make_float2(a1.x + b1.y, a1.y - b1.x);
    y[4] = make_float2(a1.x - b1.y, a1.y + b1.x);
    y[2] = make_float2(a2.x + b2.y, a2.y - b2.x);
    y[3] = make_float2(a2.x - b2.y, a2.y + b2.x);
}

__device__ __forceinline__ float2 bfly(float2 v, int m, float2 tw, int l){
    float2 o = shfl2(v, m);
    float2 s = cadd(v, o);
    float2 d = cxmul(csub(o, v), tw);
    return (l & m) ? d : s;
}

// 160-pt FFT: lane l in [0,32) holds y[n1]=x[n1*32+l] on entry.
// On exit, slot k holds X[k + 5*br5(l)].
template<int SGN>
__device__ __forceinline__ void linefft(float2 y[5], int l){
    dft5<SGN>(y);
    float2 w1 = twid<SGN>((float)l * (1.f/160.f));
    float2 w2 = cxmul(w1,w1);
    float2 w3 = cxmul(w2,w1);
    float2 w4 = cxmul(w2,w2);
    y[1]=cxmul(y[1],w1); y[2]=cxmul(y[2],w2); y[3]=cxmul(y[3],w3); y[4]=cxmul(y[4],w4);
    float2 tw16 = twid<SGN>((float)(l & 15) * (1.f/32.f));
    float2 tw8  = twid<SGN>((float)(l & 7)  * (1.f/16.f));
    float2 tw4  = twid<SGN>((float)(l & 3)  * (1.f/8.f));
    float2 tw2  = twid<SGN>((float)(l & 1)  * (1.f/4.f));
    #pragma unroll
    for (int k=0;k<5;k++){
        float2 v = y[k];
        v = bfly(v,16,tw16,l);
        v = bfly(v, 8,tw8 ,l);
        v = bfly(v, 4,tw4 ,l);
        v = bfly(v, 2,tw2 ,l);
        float2 o = shfl2(v,1);
        v = (l&1) ? csub(o,v) : cadd(v,o);
        y[k] = v;
    }
}

// DIT butterfly: low lane: v + tw*o ; high lane: o - tw*v
__device__ __forceinline__ float2 bflyi(float2 v, int m, float2 tw, int l){
    float2 o = shfl2(v, m);
    float2 t = cxmul(tw, (l & m) ? v : o);
    return (l & m) ? csub(o, t) : cadd(v, t);
}

// inverse 160-pt FFT consuming the forward's permuted register layout:
// entry: slot k lane l = X[k + 5*br5(l)]; exit: y[n1] = x[n1*32+l] (UNscaled).
__device__ __forceinline__ void ilinefft_perm(float2 y[5], int l){
    float2 tw2  = twid<-1>((float)(l & 1)  * (1.f/4.f));
    float2 tw4  = twid<-1>((float)(l & 3)  * (1.f/8.f));
    float2 tw8  = twid<-1>((float)(l & 7)  * (1.f/16.f));
    float2 tw16 = twid<-1>((float)(l & 15) * (1.f/32.f));
    #pragma unroll
    for (int k=0;k<5;k++){
        float2 v = y[k];
        { float2 o = shfl2(v,1); v = (l&1) ? csub(o,v) : cadd(v,o); }
        v = bflyi(v, 2, tw2 , l);
        v = bflyi(v, 4, tw4 , l);
        v = bflyi(v, 8, tw8 , l);
        v = bflyi(v,16, tw16, l);
        y[k] = v;
    }
    float2 w1 = twid<-1>((float)l * (1.f/160.f));
    float2 w2 = cxmul(w1,w1);
    float2 w3 = cxmul(w2,w1);
    float2 w4 = cxmul(w2,w2);
    y[1]=cxmul(y[1],w1); y[2]=cxmul(y[2],w2); y[3]=cxmul(y[3],w3); y[4]=cxmul(y[4],w4);
    dft5<-1>(y);
}

struct RPc {
    __half2* C[3];
    const __half* M[3];
};

// analytic kernel ingredients: Q sums over (dy,dz) ball slices, per column
struct QCol {
    float Q1_0, Q1_1;
    float Q2_0, Q2_1, Q2_2;
    float Q3_0, Q3_1, Q3_2, Q3_3;
    float fz2;
};

__device__ __forceinline__ QCol make_qcol(float ay0,float ay1,float ay2,float ay3, int kz){
    float fz = (float)kz * (1.f/160.f);
    float cz1 = fcos_rev(fz);
    float cz2 = 2.f*cz1*cz1 - 1.f;
    float cz3 = 2.f*cz1*cz2 - cz1;
    float az0=1.f, az1=2.f*cz1, az2=2.f*cz2, az3=2.f*cz3;
    float P00=ay0*az0, P01=ay0*az1, P02=ay0*az2, P03=ay0*az3;
    float P10=ay1*az0, P11=ay1*az1, P12=ay1*az2;
    float P20=ay2*az0, P21=ay2*az1, P22=ay2*az2;
    float P30=ay3*az0;
    QCol q;
    q.Q1_0 = P00 + P01 + P10;
    q.Q1_1 = P00;
    q.Q2_0 = P00+P01+P02+P10+P11+P20;
    q.Q2_1 = P00+P01+P10+P11;
    q.Q2_2 = P00;
    q.Q3_0 = P00+P01+P02+P03+P10+P11+P12+P20+P21+P22+P30;
    q.Q3_1 = P00+P01+P02+P10+P11+P12+P20+P21+P22;
    q.Q3_2 = P00+P01+P02+P10+P11+P12+P20+P21;
    q.Q3_3 = P00;
    q.fz2 = fz*fz;
    return q;
}

// all three K_r with one cosine chain. kx in [0,160).
__device__ __forceinline__ void kval3(const QCol& q, float fy2, int kx, float K[3]){
    float c1 = fcos_rev((float)kx * (1.f/160.f));
    float c2 = 2.f*c1*c1 - 1.f;
    float c3 = 2.f*c1*c2 - c1;
    float s1 = (q.Q1_0 + 2.f*c1*q.Q1_1) * (1.f/7.f);
    float s2 = (q.Q2_0 + 2.f*(c1*q.Q2_1 + c2*q.Q2_2)) * (1.f/33.f);
    float s3 = (q.Q3_0 + 2.f*(c1*q.Q3_1 + c2*q.Q3_2 + c3*q.Q3_3)) * (1.f/123.f);
    float fxw = (float)((kx < 80) ? kx : 160 - kx) * (1.f/160.f);
    float k2 = fxw*fxw + fy2 + q.fz2;
    float D = (1.f/3.f) - ((k2 == 0.f) ? 0.f : q.fz2 * __builtin_amdgcn_rcpf(k2));
    K[0] = (1.f - s1) * D;
    K[1] = (1.f - s2) * D;
    K[2] = (1.f - s3) * D;
}

// ---------------- CG reduction helper ----------------
__device__ __forceinline__ void block_atomic_add(double v, double* target){
    #pragma unroll
    for (int off=32; off>0; off>>=1) v += __shfl_down(v, off, 64);
    __shared__ double sm[4];
    int wv = threadIdx.x >> 6;
    if ((threadIdx.x & 63) == 0) sm[wv] = v;
    __syncthreads();
    if (threadIdx.x == 0) atomicAdd(target, sm[0]+sm[1]+sm[2]+sm[3]);
}

// ======== z-axis kernels: wave-local, barrier-free ========
// Forward passes carry 1/160 each axis; inverse passes are UNscaled.
// PM=0: fft real zin. PM=1: p = r + beta*p (beta=S[3]), store p, fft p.
template<int PM>
__global__ __launch_bounds__(256) void fft_z_first(const float* __restrict__ zin,
    const float* __restrict__ rrv, float* __restrict__ ppv,
    __half2* __restrict__ out, const double* __restrict__ S)
{
    __shared__ float2 ldsC[8*162];
    int tid = threadIdx.x, l = tid & 31, g = tid >> 5;
    int fl = g*162;
    size_t base160 = (size_t)blockIdx.x * 2560 + (size_t)(2*g)*160;
    size_t baseC   = (size_t)blockIdx.x * 1296 + (size_t)g*162;
    float beta = PM ? (float)S[3] : 0.f;
    float2 y[5];
    #pragma unroll
    for (int n1=0;n1<5;n1++){
        int n = n1*32 + l;
        float a, b;
        if (PM){
            a = rrv[base160 + n]       + beta * ppv[base160 + n];
            b = rrv[base160 + 160 + n] + beta * ppv[base160 + 160 + n];
            ppv[base160 + n] = a;
            ppv[base160 + 160 + n] = b;
        } else {
            a = zin[base160 + n];
            b = zin[base160 + 160 + n];
        }
        y[n1] = make_float2(a * SC160, b * SC160);   // fwd 1/160
    }
    linefft<1>(y, l);
    int o5 = 5*br5(l);
    #pragma unroll
    for (int k=0;k<5;k++) ldsC[fl + o5 + k] = y[k];
    #pragma unroll
    for (int t=0;t<6;t++){
        int j = l + 32*t;
        if (j < 162){
            int k = (j < 81) ? j : j - 81;
            float2 Sk = ldsC[fl + k];
            float2 Sm = ldsC[fl + ((160 - k) % 160)];
            float2 o = (j >= 81)
                ? make_float2(0.5f*(Sk.y + Sm.y), -0.5f*(Sk.x - Sm.x))    // B
                : make_float2(0.5f*(Sk.x + Sm.x),  0.5f*(Sk.y - Sm.y));   // A
            out[baseC + j] = f2h(o);
        }
    }
}

// fused: inverse-z (unscaled) -> *(m2w_r/160) -> forward-z
template<bool PRE>
__global__ __launch_bounds__(256) void fft_z_mid3(RPc P, const float* __restrict__ mask,
                                                 const float* __restrict__ wfull)
{
    __shared__ float2 ldsC[8*162];
    int r = blockIdx.y;
    __half2* C = P.C[r];
    int tid = threadIdx.x, l = tid & 31, g = tid >> 5;
    int fl = g*162;
    size_t baseC   = (size_t)blockIdx.x * 1296 + (size_t)g*162;
    size_t base160 = (size_t)blockIdx.x * 2560 + (size_t)(2*g)*160;
    int o5 = 5*br5(l);
    float ma[5], mb[5];
    if (PRE){
        const __half* M = P.M[r];
        #pragma unroll
        for (int k=0;k<5;k++){
            ma[k] = __half2float(M[base160 + o5 + k]) * SC160;
            mb[k] = __half2float(M[base160 + 160 + o5 + k]) * SC160;
        }
    } else {
        #pragma unroll
        for (int k=0;k<5;k++){
            size_t ia = base160 + o5 + k, ib = base160 + 160 + o5 + k;
            float m1 = mask[ia], m2 = mask[ib];
            ma[k] = m1*m1*wfull[ia*3 + r] * SC160;
            mb[k] = m2*m2*wfull[ib*3 + r] * SC160;
        }
    }
    #pragma unroll
    for (int t=0;t<6;t++){
        int j = l + 32*t;
        if (j < 162) ldsC[fl + j] = h2f(C[baseC + j]);
    }
    float2 y[5];
    #pragma unroll
    for (int n1=0;n1<5;n1++){
        int e = n1*32 + l;
        float2 X;
        if (e <= 80){
            float2 A = ldsC[fl + e], B = ldsC[fl + 81 + e];
            X = make_float2(A.x - B.y, A.y + B.x);
        } else {
            int m = 160 - e;
            float2 A = ldsC[fl + m], B = ldsC[fl + 81 + m];
            X = make_float2(A.x + B.y, B.x - A.y);
        }
        y[n1] = X;
    }
    linefft<-1>(y, l);
    #pragma unroll
    for (int k=0;k<5;k++){
        float a = y[k].x * ma[k];
        float b = y[k].y * mb[k];
        ldsC[fl + o5 + k] = make_float2(a, b);
    }
    #pragma unroll
    for (int n1=0;n1<5;n1++) y[n1] = ldsC[fl + n1*32 + l];
    linefft<1>(y, l);
    #pragma unroll
    for (int k=0;k<5;k++) ldsC[fl + o5 + k] = y[k];
    #pragma unroll
    for (int t=0;t<6;t++){
        int j = l + 32*t;
        if (j < 162){
            int k = (j < 81) ? j : j - 81;
            float2 Sk = ldsC[fl + k];
            float2 Sm = ldsC[fl + ((160 - k) % 160)];
            float2 o = (j >= 81)
                ? make_float2(0.5f*(Sk.y + Sm.y), -0.5f*(Sk.x - Sm.x))
                : make_float2(0.5f*(Sk.x + Sm.x),  0.5f*(Sk.y - Sm.y));
            C[baseC + j] = f2h(o);
        }
    }
}

// final inverse-z (unscaled) + epilogue.
// FIN=0: Ap=v, S[1]+=<z,v>. FIN=1: r=b-v -> rr,pp, S[0]+=<r,r>.
template<int FIN>
__global__ __launch_bounds__(256) void fft_z_fin(const __half2* __restrict__ in,
    const float* __restrict__ zsp, float* __restrict__ Ap,
    const float* __restrict__ bb, float* __restrict__ rrv, float* __restrict__ ppv,
    double* __restrict__ S)
{
    __shared__ float2 ldsC[8*162];
    float* ldsF = (float*)ldsC;      // region g: floats [324g, 324g+320)
    int tid = threadIdx.x, l = tid & 31, g = tid >> 5;
    int fl = g*162;
    size_t baseC   = (size_t)blockIdx.x * 1296 + (size_t)g*162;
    size_t base160 = (size_t)blockIdx.x * 2560 + (size_t)(2*g)*160;
    int o5 = 5*br5(l);
    float za[5], zb[5], pa[5], pb[5];
    #pragma unroll
    for (int k=0;k<5;k++){
        za[k] = zsp[base160 + o5 + k];
        zb[k] = zsp[base160 + 160 + o5 + k];
        if (FIN){
            pa[k] = bb[base160 + o5 + k];
            pb[k] = bb[base160 + 160 + o5 + k];
        }
    }
    #pragma unroll
    for (int t=0;t<6;t++){
        int j = l + 32*t;
        if (j < 162) ldsC[fl + j] = h2f(in[baseC + j]);
    }
    float2 y[5];
    #pragma unroll
    for (int n1=0;n1<5;n1++){
        int e = n1*32 + l;
        float2 X;
        if (e <= 80){
            float2 A = ldsC[fl + e], B = ldsC[fl + 81 + e];
            X = make_float2(A.x - B.y, A.y + B.x);
        } else {
            int m = 160 - e;
            float2 A = ldsC[fl + m], B = ldsC[fl + 81 + m];
            X = make_float2(A.x + B.y, B.x - A.y);
        }
        y[n1] = X;
    }
    linefft<-1>(y, l);
    double acc = 0.0;
    int fb = g*324;
    #pragma unroll
    for (int k=0;k<5;k++){
        float va = LAM_F*za[k] + y[k].x;      // inverse unscaled
        float vb = LAM_F*zb[k] + y[k].y;
        if (FIN == 0){
            acc += (double)za[k]*(double)va + (double)zb[k]*(double)vb;
            ldsF[fb + o5 + k] = va;
            ldsF[fb + 160 + o5 + k] = vb;
        } else {
            float ra = pa[k] - va, rb = pb[k] - vb;
            acc += (double)ra*(double)ra + (double)rb*(double)rb;
            ldsF[fb + o5 + k] = ra;
            ldsF[fb + 160 + o5 + k] = rb;
        }
    }
    #pragma unroll
    for (int t=0;t<10;t++){
        int n = l + 32*t;
        float v = ldsF[fb + n];
        if (FIN == 0){
            Ap[base160 + n] = v;
        } else {
            rrv[base160 + n] = v;
            ppv[base160 + n] = v;
        }
    }
    block_atomic_add(acc, FIN ? &S[0] : &S[1]);
}

// ---------------- y-axis sweeps (strided, guarded half-spectrum, W=8) ----------------
// SGN>0 (fwd): scale 1/160 ; SGN<0 (inv): unscaled.
template<int SGN>
__device__ __forceinline__ void ycompute(float2 (*tile)[WZ+1], int tid){
    int l = tid & 31, q = tid >> 5;
    const float SC = (SGN>0) ? SC160 : 1.f;
    float2 y[5];
    #pragma unroll
    for (int n1=0;n1<5;n1++) y[n1] = tile[l + 32*n1][q];
    linefft<SGN>(y, l);
    int o5 = 5*br5(l);
    #pragma unroll
    for (int k=0;k<5;k++) tile[o5+k][q] = cscale(y[k], SC);
}

// b = zchunk*160 + ix  (zb-outer so line-sharing blocks b, b+160 share an XCD)
template<int SGN>
__global__ __launch_bounds__(256) void fft_y1(__half2* __restrict__ data)
{
    __shared__ float2 tile[NN][WZ+1];
    int b = blockIdx.x;
    int ix = b % 160, zb = (b / 160) * WZ;
    size_t tbase = (size_t)ix*XS + zb;
    int tid = threadIdx.x;
    for (int i = tid; i < NN*WZ; i += 256){
        int row = i >> 3, zi = i & 7;
        tile[row][zi] = (zb + zi < KP) ? h2f(data[tbase + (size_t)row*KP + zi]) : make_float2(0.f,0.f);
    }
    __syncthreads();
    ycompute<SGN>(tile, tid);
    __syncthreads();
    for (int i = tid; i < NN*WZ; i += 256){
        int row = i >> 3, zi = i & 7;
        if (zb + zi < KP) data[tbase + (size_t)row*KP + zi] = f2h(tile[row][zi]);
    }
}

template<int SGN>
__global__ __launch_bounds__(256) void fft_y3(RPc P)
{
    __shared__ float2 tile[NN][WZ+1];
    __half2* data = P.C[blockIdx.y];
    int b = blockIdx.x;
    int ix = b % 160, zb = (b / 160) * WZ;
    size_t tbase = (size_t)ix*XS + zb;
    int tid = threadIdx.x;
    for (int i = tid; i < NN*WZ; i += 256){
        int row = i >> 3, zi = i & 7;
        tile[row][zi] = (zb + zi < KP) ? h2f(data[tbase + (size_t)row*KP + zi]) : make_float2(0.f,0.f);
    }
    __syncthreads();
    ycompute<SGN>(tile, tid);
    __syncthreads();
    for (int i = tid; i < NN*WZ; i += 256){
        int row = i >> 3, zi = i & 7;
        if (zb + zi < KP) data[tbase + (size_t)row*KP + zi] = f2h(tile[row][zi]);
    }
}

// ---------------- x-axis kernels with analytic K (W=4, 128 threads) ----------------
// spread: one block per (iy, 4-col zb chunk). Own-column loads, shared fwd-x
// FFT once, 3 tiles with zero intervening barriers, one barrier, 3 coop stores.
__global__ __launch_bounds__(128) void fft_xK(RPc P, const __half2* __restrict__ in)
{
    __shared__ __half2 t0[NN][XW+1], t1[NN][XW+1], t2[NN][XW+1];
    int b = blockIdx.x;
    int iy = b % 160, zb = (b / 160) * XW;
    size_t tbase = (size_t)iy*KP + zb;
    int tid = threadIdx.x, l = tid & 31, q = tid >> 5;   // q in [0,4)
    bool okc = (zb + q < KP);
    float2 spec[5];
    #pragma unroll
    for (int n1=0;n1<5;n1++){
        int row = n1*32 + l;
        spec[n1] = okc ? h2f(in[tbase + (size_t)row*XS + q]) : make_float2(0.f,0.f);
    }
    float fy = (float)((iy < 80) ? iy : iy - 160) * (1.f/160.f);
    float fy2 = fy*fy;
    float cy1 = fcos_rev(fy);
    float cy2 = 2.f*cy1*cy1 - 1.f;
    float cy3 = 2.f*cy1*cy2 - cy1;
    QCol qc = make_qcol(1.f, 2.f*cy1, 2.f*cy2, 2.f*cy3, zb + q);
    int o5 = 5*br5(l);
    linefft<1>(spec, l);
    float K3[5][3];
    #pragma unroll
    for (int k=0;k<5;k++) kval3(qc, fy2, o5+k, K3[k]);
    {
        float2 a[5];
        #pragma unroll
        for (int k=0;k<5;k++) a[k] = cscale(spec[k], K3[k][0] * SC160);
        ilinefft_perm(a, l);
        #pragma unroll
        for (int n1=0;n1<5;n1++) t0[n1*32 + l][q] = f2h(a[n1]);
    }
    {
        float2 a[5];
        #pragma unroll
        for (int k=0;k<5;k++) a[k] = cscale(spec[k], K3[k][1] * SC160);
        ilinefft_perm(a, l);
        #pragma unroll
        for (int n1=0;n1<5;n1++) t1[n1*32 + l][q] = f2h(a[n1]);
    }
    {
        float2 a[5];
        #pragma unroll
        for (int k=0;k<5;k++) a[k] = cscale(spec[k], K3[k][2] * SC160);
        ilinefft_perm(a, l);
        #pragma unroll
        for (int n1=0;n1<5;n1++) t2[n1*32 + l][q] = f2h(a[n1]);
    }
    __syncthreads();
    {
        __half2* Cr = P.C[0];
        for (int i = tid; i < NN*XW; i += 128){
            int row = i >> 2, zi = i & 3;
            if (zb + zi < KP) Cr[tbase + (size_t)row*XS + zi] = t0[row][zi];
        }
    }
    {
        __half2* Cr = P.C[1];
        for (int i = tid; i < NN*XW; i += 128){
            int row = i >> 2, zi = i & 3;
            if (zb + zi < KP) Cr[tbase + (size_t)row*XS + zi] = t1[row][zi];
        }
    }
    {
        __half2* Cr = P.C[2];
        for (int i = tid; i < NN*XW; i += 128){
            int row = i >> 2, zi = i & 3;
            if (zb + zi < KP) Cr[tbase + (size_t)row*XS + zi] = t2[row][zi];
        }
    }
}

// gather: CF = invx( sum_r (K_r/160) * fwdx(C_r) ). W=4, 128 threads.
// Hoisted own-column loads; one barrier before the final store-transpose.
__global__ __launch_bounds__(128) void fft_xgather(RPc P, __half2* __restrict__ out)
{
    __shared__ __half2 tile[NN][XW+1];
    int b = blockIdx.x;
    int iy = b % 160, zb = (b / 160) * XW;
    size_t tbase = (size_t)iy*KP + zb;
    int tid = threadIdx.x, l = tid & 31, q = tid >> 5;
    bool okc = (zb + q < KP);
    float2 v0[5], v1[5], v2[5];
    #pragma unroll
    for (int n1=0;n1<5;n1++){
        size_t a = tbase + (size_t)(n1*32 + l)*XS + q;
        v0[n1] = okc ? h2f(P.C[0][a]) : make_float2(0.f,0.f);
        v1[n1] = okc ? h2f(P.C[1][a]) : make_float2(0.f,0.f);
        v2[n1] = okc ? h2f(P.C[2][a]) : make_float2(0.f,0.f);
    }
    float fy = (float)((iy < 80) ? iy : iy - 160) * (1.f/160.f);
    float fy2 = fy*fy;
    float cy1 = fcos_rev(fy);
    float cy2 = 2.f*cy1*cy1 - 1.f;
    float cy3 = 2.f*cy1*cy2 - cy1;
    QCol qc = make_qcol(1.f, 2.f*cy1, 2.f*cy2, 2.f*cy3, zb + q);
    int o5 = 5*br5(l);
    float K3[5][3];
    #pragma unroll
    for (int k=0;k<5;k++) kval3(qc, fy2, o5+k, K3[k]);
    float2 acc[5];
    linefft<1>(v0, l);
    #pragma unroll
    for (int k=0;k<5;k++) acc[k] = cscale(v0[k], K3[k][0] * SC160);
    linefft<1>(v1, l);
    #pragma unroll
    for (int k=0;k<5;k++) acc[k] = cadd(acc[k], cscale(v1[k], K3[k][1] * SC160));
    linefft<1>(v2, l);
    #pragma unroll
    for (int k=0;k<5;k++) acc[k] = cadd(acc[k], cscale(v2[k], K3[k][2] * SC160));
    ilinefft_perm(acc, l);
    #pragma unroll
    for (int n1=0;n1<5;n1++) tile[n1*32 + l][q] = f2h(acc[n1]);
    __syncthreads();
    for (int i = tid; i < NN*XW; i += 128){
        int row = i >> 2, zi = i & 3;
        if (zb + zi < KP) out[tbase + (size_t)row*XS + zi] = tile[row][zi];
    }
}

// ---------------- setup / CG vector ops ----------------
__global__ __launch_bounds__(256) void m2w_kernel(const float* __restrict__ mask,
        const float* __restrict__ w, __half* __restrict__ M0,
        __half* __restrict__ M1, __half* __restrict__ M2)
{
    int i = blockIdx.x*256 + threadIdx.x;
    float m = mask[i]; float mm = m*m;
    M0[i] = __float2half(mm * w[3*(size_t)i+0]);
    M1[i] = __float2half(mm * w[3*(size_t)i+1]);
    M2[i] = __float2half(mm * w[3*(size_t)i+2]);
}

__global__ __launch_bounds__(256) void copy_kernel(const float* __restrict__ a, float* __restrict__ b){
    int i = blockIdx.x*256 + threadIdx.x;
    b[i] = a[i];
}

#define GSTRIDE (2048*256)
__global__ __launch_bounds__(256) void upd1_kernel(float* __restrict__ x, float* __restrict__ r,
        const float* __restrict__ p, const float* __restrict__ Ap, double* s)
{
    float alpha = (float)(s[0] / (s[1] + 1e-12));
    double acc = 0.0;
    for (int i = blockIdx.x*256 + threadIdx.x; i < N3; i += GSTRIDE){
        x[i] += alpha * p[i];
        float rn = r[i] - alpha * Ap[i];
        r[i] = rn;
        acc += (double)rn * (double)rn;
    }
    block_atomic_add(acc, &s[2]);
}
__global__ void advance_kernel(double* s){
    if (threadIdx.x == 0){
        s[3] = s[2] / (s[0] + 1e-12);   // beta
        s[0] = s[2]; s[1] = 0.0; s[2] = 0.0;
    }
}
__global__ void zero_kernel(double* s){
    if (threadIdx.x < 4) s[threadIdx.x] = 0.0;
}

// ---------------- host orchestration ----------------
extern "C" void kernel_launch(void* const* d_in, const int* in_sizes, int n_in,
                              void* d_out, int out_size, void* d_ws, size_t ws_size,
                              hipStream_t stream)
{
    (void)in_sizes; (void)n_in; (void)out_size;
    const float* w    = (const float*)d_in[0];   // [N3*3], R fastest
    const float* x2   = (const float*)d_in[1];   // [N3]
    const float* mask = (const float*)d_in[2];   // [N3]
    const float* bb   = (const float*)d_in[3];   // [N3]
    float* x = (float*)d_out;
    char* ws = (char*)d_ws;

    size_t off = 0;
    auto alloc = [&](size_t bytes)->void*{
        void* pp = ws + off;
        off += (bytes + 255) & ~(size_t)255;
        return pp;
    };
    const size_t CB = (size_t)NLINES * KP * sizeof(__half2);   // 8.3 MB
    __half2* CF = (__half2*)alloc(CB);
    __half2* C0 = (__half2*)alloc(CB);
    __half2* C1 = (__half2*)alloc(CB);
    __half2* C2 = (__half2*)alloc(CB);
    float*  rr = (float*) alloc((size_t)N3*4);
    float*  pp = (float*) alloc((size_t)N3*4);
    float*  Ap = (float*) alloc((size_t)N3*4);
    double* S  = (double*)alloc(64);
    bool PRE = (ws_size >= off + 3*(((size_t)N3*2 + 255) & ~(size_t)255));
    __half *M0=nullptr, *M1=nullptr, *M2=nullptr;
    if (PRE){
        M0 = (__half*)alloc((size_t)N3*2);
        M1 = (__half*)alloc((size_t)N3*2);
        M2 = (__half*)alloc((size_t)N3*2);
    }
    RPc P;
    P.C[0]=C0; P.C[1]=C1; P.C[2]=C2;
    P.M[0]=M0; P.M[1]=M1; P.M[2]=M2;

    zero_kernel<<<1, 64, 0, stream>>>(S);
    if (PRE) m2w_kernel<<<16000, 256, 0, stream>>>(mask, w, M0, M1, M2);
    copy_kernel<<<16000, 256, 0, stream>>>(x2, x);

    const int GY = NBZ * 160;    // 1760 (y kernels, W=8)
    const int GX4 = NBX4 * 160;  // 3360 (x kernels, W=4)
    // PM: 0 = plain fft of z; 1 = fused p-update. FIN: 1 = initial residual, 0 = CG iter.
    auto applyM = [&](const float* z, int FIN, int PM){
        if (PM) fft_z_first<1><<<1600, 256, 0, stream>>>(z, rr, pp, CF, S);
        else    fft_z_first<0><<<1600, 256, 0, stream>>>(z, rr, pp, CF, S);
        fft_y1<1><<<GY, 256, 0, stream>>>(CF);
        fft_xK<<<GX4, 128, 0, stream>>>(P, CF);
        fft_y3<-1><<<dim3(GY,3), 256, 0, stream>>>(P);
        if (PRE) fft_z_mid3<true ><<<dim3(1600,3), 256, 0, stream>>>(P, mask, w);
        else     fft_z_mid3<false><<<dim3(1600,3), 256, 0, stream>>>(P, mask, w);
        fft_y3<1><<<dim3(GY,3), 256, 0, stream>>>(P);
        fft_xgather<<<GX4, 128, 0, stream>>>(P, CF);
        fft_y1<-1><<<GY, 256, 0, stream>>>(CF);
        if (FIN) fft_z_fin<1><<<1600, 256, 0, stream>>>(CF, x, Ap, bb, rr, pp, S);
        else     fft_z_fin<0><<<1600, 256, 0, stream>>>(CF, pp, Ap, bb, rr, pp, S);
    };

    // r = b - M(x2); p = r; rs = <r,r>
    applyM(x, 1, 0);

    for (int it = 0; it < 10; it++){
        applyM(pp, 0, (it == 0) ? 0 : 1);          // Ap = M(p), S[1] = <p,Ap>
        upd1_kernel<<<2048, 256, 0, stream>>>(x, rr, pp, Ap, S);
        if (it < 9) advance_kernel<<<1, 64, 0, stream>>>(S);
    }
}

// Round 16
// 2556.950 us; speedup vs baseline: 1.0012x; 1.0012x over previous
//
#include <hip/hip_runtime.h>
#include <hip/hip_fp16.h>

#define NN 160
#define KP 81                // kept kz planes (Hermitian half)
#define N3 4096000           // 160^3
#define NLINES 25600         // 160^2 z-lines
#define WZ 8                 // tile width (kz columns) for y sweeps
#define NBZ 11               // ceil(81/8)
#define XW 4                 // tile width for x sweeps (128-thread blocks)
#define NBX4 21              // ceil(81/4)
#define XS 12960             // x-stride in complex layout (160*81)
#define TPI 6.28318530717958647692f
#define LAM_F 0.05f
#define SC160 (1.f/160.f)

// ---------------- complex helpers ----------------
__device__ __forceinline__ float2 cxmul(float2 a, float2 b){
    return make_float2(a.x*b.x - a.y*b.y, a.x*b.y + a.y*b.x);
}
__device__ __forceinline__ float2 cadd(float2 a, float2 b){ return make_float2(a.x+b.x, a.y+b.y); }
__device__ __forceinline__ float2 csub(float2 a, float2 b){ return make_float2(a.x-b.x, a.y-b.y); }
__device__ __forceinline__ float2 cscale(float2 a, float s){ return make_float2(a.x*s, a.y*s); }
__device__ __forceinline__ float2 shfl2(float2 v, int m){
    return make_float2(__shfl_xor(v.x, m, 64), __shfl_xor(v.y, m, 64));
}
__device__ __forceinline__ int br5(int l){
    return ((l&1)<<4)|((l&2)<<2)|(l&4)|((l&8)>>2)|((l&16)>>4);
}
__device__ __forceinline__ float2 h2f(__half2 h){ return __half22float2(h); }
__device__ __forceinline__ __half2 f2h(float2 f){ return __float22half2_rn(f); }
// rev in revolutions (angle/2pi). v_sin_f32/v_cos_f32 are revolution-input
// on gfx950 -> 1 instr each, no range reduction needed.
__device__ __forceinline__ float fsin_rev(float rev){ return __builtin_amdgcn_sinf(rev); }
__device__ __forceinline__ float fcos_rev(float rev){ return __builtin_amdgcn_cosf(rev); }
template<int SGN>
__device__ __forceinline__ float2 twid(float rev){
    float s = fsin_rev(rev), c = fcos_rev(rev);
    return make_float2(c, (SGN>0) ? -s : s);
}

// ---------------- radix-5 DFT ----------------
template<int SGN>
__device__ __forceinline__ void dft5(float2 y[5]){
    const float C1 = 0.30901699437494742f;
    const float C2 = -0.80901699437494742f;
    const float S1 = 0.95105651629515357f;
    const float S2 = 0.58778525229247312f;
    float2 x0=y[0], x1=y[1], x2=y[2], x3=y[3], x4=y[4];
    float2 t1=cadd(x1,x4), t2=cadd(x2,x3), t3=csub(x1,x4), t4=csub(x2,x3);
    y[0] = cadd(x0, cadd(t1,t2));
    float2 a1 = make_float2(x0.x + C1*t1.x + C2*t2.x, x0.y + C1*t1.y + C2*t2.y);
    float2 a2 = make_float2(x0.x + C2*t1.x + C1*t2.x, x0.y + C2*t1.y + C1*t2.y);
    const float sg = (SGN>0) ? 1.f : -1.f;
    float2 b1 = make_float2(sg*(S1*t3.x + S2*t4.x), sg*(S1*t3.y + S2*t4.y));
    float2 b2 = make_float2(sg*(S2*t3.x - S1*t4.x), sg*(S2*t3.y - S1*t4.y));
    y[1] = make_float2(a1.x + b1.y, a1.y - b1.x);
    y[4] = make_float2(a1.x - b1.y, a1.y + b1.x);
    y[2] = make_float2(a2.x + b2.y, a2.y - b2.x);
    y[3] = make_float2(a2.x - b2.y, a2.y + b2.x);
}

__device__ __forceinline__ float2 bfly(float2 v, int m, float2 tw, int l){
    float2 o = shfl2(v, m);
    float2 s = cadd(v, o);
    float2 d = cxmul(csub(o, v), tw);
    return (l & m) ? d : s;
}

// 160-pt FFT: lane l in [0,32) holds y[n1]=x[n1*32+l] on entry.
// On exit, slot k holds X[k + 5*br5(l)].
template<int SGN>
__device__ __forceinline__ void linefft(float2 y[5], int l){
    dft5<SGN>(y);
    float2 w1 = twid<SGN>((float)l * (1.f/160.f));
    float2 w2 = cxmul(w1,w1);
    float2 w3 = cxmul(w2,w1);
    float2 w4 = cxmul(w2,w2);
    y[1]=cxmul(y[1],w1); y[2]=cxmul(y[2],w2); y[3]=cxmul(y[3],w3); y[4]=cxmul(y[4],w4);
    float2 tw16 = twid<SGN>((float)(l & 15) * (1.f/32.f));
    float2 tw8  = twid<SGN>((float)(l & 7)  * (1.f/16.f));
    float2 tw4  = twid<SGN>((float)(l & 3)  * (1.f/8.f));
    float2 tw2  = twid<SGN>((float)(l & 1)  * (1.f/4.f));
    #pragma unroll
    for (int k=0;k<5;k++){
        float2 v = y[k];
        v = bfly(v,16,tw16,l);
        v = bfly(v, 8,tw8 ,l);
        v = bfly(v, 4,tw4 ,l);
        v = bfly(v, 2,tw2 ,l);
        float2 o = shfl2(v,1);
        v = (l&1) ? csub(o,v) : cadd(v,o);
        y[k] = v;
    }
}

// DIT butterfly: low lane: v + tw*o ; high lane: o - tw*v
__device__ __forceinline__ float2 bflyi(float2 v, int m, float2 tw, int l){
    float2 o = shfl2(v, m);
    float2 t = cxmul(tw, (l & m) ? v : o);
    return (l & m) ? csub(o, t) : cadd(v, t);
}

// inverse 160-pt FFT consuming the forward's permuted register layout:
// entry: slot k lane l = X[k + 5*br5(l)]; exit: y[n1] = x[n1*32+l] (UNscaled).
__device__ __forceinline__ void ilinefft_perm(float2 y[5], int l){
    float2 tw2  = twid<-1>((float)(l & 1)  * (1.f/4.f));
    float2 tw4  = twid<-1>((float)(l & 3)  * (1.f/8.f));
    float2 tw8  = twid<-1>((float)(l & 7)  * (1.f/16.f));
    float2 tw16 = twid<-1>((float)(l & 15) * (1.f/32.f));
    #pragma unroll
    for (int k=0;k<5;k++){
        float2 v = y[k];
        { float2 o = shfl2(v,1); v = (l&1) ? csub(o,v) : cadd(v,o); }
        v = bflyi(v, 2, tw2 , l);
        v = bflyi(v, 4, tw4 , l);
        v = bflyi(v, 8, tw8 , l);
        v = bflyi(v,16, tw16, l);
        y[k] = v;
    }
    float2 w1 = twid<-1>((float)l * (1.f/160.f));
    float2 w2 = cxmul(w1,w1);
    float2 w3 = cxmul(w2,w1);
    float2 w4 = cxmul(w2,w2);
    y[1]=cxmul(y[1],w1); y[2]=cxmul(y[2],w2); y[3]=cxmul(y[3],w3); y[4]=cxmul(y[4],w4);
    dft5<-1>(y);
}

// ======== batched-by-3 FFTs: stage-interleaved for shuffle-latency ILP ========
// forward, 3 independent lines (same lane geometry, shared twiddles)
template<int SGN>
__device__ __forceinline__ void linefft_b3(float2 y[3][5], int l){
    for (int j=0;j<3;j++) dft5<SGN>(y[j]);
    float2 w1 = twid<SGN>((float)l * (1.f/160.f));
    float2 w2 = cxmul(w1,w1);
    float2 w3 = cxmul(w2,w1);
    float2 w4 = cxmul(w2,w2);
    #pragma unroll
    for (int j=0;j<3;j++){
        y[j][1]=cxmul(y[j][1],w1); y[j][2]=cxmul(y[j][2],w2);
        y[j][3]=cxmul(y[j][3],w3); y[j][4]=cxmul(y[j][4],w4);
    }
    float2 tw16 = twid<SGN>((float)(l & 15) * (1.f/32.f));
    float2 tw8  = twid<SGN>((float)(l & 7)  * (1.f/16.f));
    float2 tw4  = twid<SGN>((float)(l & 3)  * (1.f/8.f));
    float2 tw2  = twid<SGN>((float)(l & 1)  * (1.f/4.f));
    float2 o[3][5];
    // stage 16
    #pragma unroll
    for (int j=0;j<3;j++)
        for (int k=0;k<5;k++) o[j][k] = shfl2(y[j][k],16);
    #pragma unroll
    for (int j=0;j<3;j++)
        for (int k=0;k<5;k++){
            float2 v = y[j][k];
            y[j][k] = (l&16) ? cxmul(csub(o[j][k], v), tw16) : cadd(v, o[j][k]);
        }
    // stage 8
    #pragma unroll
    for (int j=0;j<3;j++)
        for (int k=0;k<5;k++) o[j][k] = shfl2(y[j][k],8);
    #pragma unroll
    for (int j=0;j<3;j++)
        for (int k=0;k<5;k++){
            float2 v = y[j][k];
            y[j][k] = (l&8) ? cxmul(csub(o[j][k], v), tw8) : cadd(v, o[j][k]);
        }
    // stage 4
    #pragma unroll
    for (int j=0;j<3;j++)
        for (int k=0;k<5;k++) o[j][k] = shfl2(y[j][k],4);
    #pragma unroll
    for (int j=0;j<3;j++)
        for (int k=0;k<5;k++){
            float2 v = y[j][k];
            y[j][k] = (l&4) ? cxmul(csub(o[j][k], v), tw4) : cadd(v, o[j][k]);
        }
    // stage 2
    #pragma unroll
    for (int j=0;j<3;j++)
        for (int k=0;k<5;k++) o[j][k] = shfl2(y[j][k],2);
    #pragma unroll
    for (int j=0;j<3;j++)
        for (int k=0;k<5;k++){
            float2 v = y[j][k];
            y[j][k] = (l&2) ? cxmul(csub(o[j][k], v), tw2) : cadd(v, o[j][k]);
        }
    // stage 1
    #pragma unroll
    for (int j=0;j<3;j++)
        for (int k=0;k<5;k++) o[j][k] = shfl2(y[j][k],1);
    #pragma unroll
    for (int j=0;j<3;j++)
        for (int k=0;k<5;k++){
            float2 v = y[j][k];
            y[j][k] = (l&1) ? csub(o[j][k], v) : cadd(v, o[j][k]);
        }
}

// inverse-from-permuted, 3 independent lines, stage-interleaved
__device__ __forceinline__ void ilinefft_perm_b3(float2 y[3][5], int l){
    float2 tw2  = twid<-1>((float)(l & 1)  * (1.f/4.f));
    float2 tw4  = twid<-1>((float)(l & 3)  * (1.f/8.f));
    float2 tw8  = twid<-1>((float)(l & 7)  * (1.f/16.f));
    float2 tw16 = twid<-1>((float)(l & 15) * (1.f/32.f));
    float2 o[3][5];
    // stage mask 1 (add/sub)
    #pragma unroll
    for (int j=0;j<3;j++)
        for (int k=0;k<5;k++) o[j][k] = shfl2(y[j][k],1);
    #pragma unroll
    for (int j=0;j<3;j++)
        for (int k=0;k<5;k++){
            float2 v = y[j][k];
            y[j][k] = (l&1) ? csub(o[j][k], v) : cadd(v, o[j][k]);
        }
    // DIT stage 2
    #pragma unroll
    for (int j=0;j<3;j++)
        for (int k=0;k<5;k++) o[j][k] = shfl2(y[j][k],2);
    #pragma unroll
    for (int j=0;j<3;j++)
        for (int k=0;k<5;k++){
            float2 v = y[j][k];
            float2 t = cxmul(tw2, (l&2) ? v : o[j][k]);
            y[j][k] = (l&2) ? csub(o[j][k], t) : cadd(v, t);
        }
    // DIT stage 4
    #pragma unroll
    for (int j=0;j<3;j++)
        for (int k=0;k<5;k++) o[j][k] = shfl2(y[j][k],4);
    #pragma unroll
    for (int j=0;j<3;j++)
        for (int k=0;k<5;k++){
            float2 v = y[j][k];
            float2 t = cxmul(tw4, (l&4) ? v : o[j][k]);
            y[j][k] = (l&4) ? csub(o[j][k], t) : cadd(v, t);
        }
    // DIT stage 8
    #pragma unroll
    for (int j=0;j<3;j++)
        for (int k=0;k<5;k++) o[j][k] = shfl2(y[j][k],8);
    #pragma unroll
    for (int j=0;j<3;j++)
        for (int k=0;k<5;k++){
            float2 v = y[j][k];
            float2 t = cxmul(tw8, (l&8) ? v : o[j][k]);
            y[j][k] = (l&8) ? csub(o[j][k], t) : cadd(v, t);
        }
    // DIT stage 16
    #pragma unroll
    for (int j=0;j<3;j++)
        for (int k=0;k<5;k++) o[j][k] = shfl2(y[j][k],16);
    #pragma unroll
    for (int j=0;j<3;j++)
        for (int k=0;k<5;k++){
            float2 v = y[j][k];
            float2 t = cxmul(tw16, (l&16) ? v : o[j][k]);
            y[j][k] = (l&16) ? csub(o[j][k], t) : cadd(v, t);
        }
    float2 w1 = twid<-1>((float)l * (1.f/160.f));
    float2 w2 = cxmul(w1,w1);
    float2 w3 = cxmul(w2,w1);
    float2 w4 = cxmul(w2,w2);
    #pragma unroll
    for (int j=0;j<3;j++){
        y[j][1]=cxmul(y[j][1],w1); y[j][2]=cxmul(y[j][2],w2);
        y[j][3]=cxmul(y[j][3],w3); y[j][4]=cxmul(y[j][4],w4);
        dft5<-1>(y[j]);
    }
}

struct RPc {
    __half2* C[3];
    const __half* M[3];
};

// analytic kernel ingredients: Q sums over (dy,dz) ball slices, per column
struct QCol {
    float Q1_0, Q1_1;
    float Q2_0, Q2_1, Q2_2;
    float Q3_0, Q3_1, Q3_2, Q3_3;
    float fz2;
};

__device__ __forceinline__ QCol make_qcol(float ay0,float ay1,float ay2,float ay3, int kz){
    float fz = (float)kz * (1.f/160.f);
    float cz1 = fcos_rev(fz);
    float cz2 = 2.f*cz1*cz1 - 1.f;
    float cz3 = 2.f*cz1*cz2 - cz1;
    float az0=1.f, az1=2.f*cz1, az2=2.f*cz2, az3=2.f*cz3;
    float P00=ay0*az0, P01=ay0*az1, P02=ay0*az2, P03=ay0*az3;
    float P10=ay1*az0, P11=ay1*az1, P12=ay1*az2;
    float P20=ay2*az0, P21=ay2*az1, P22=ay2*az2;
    float P30=ay3*az0;
    QCol q;
    q.Q1_0 = P00 + P01 + P10;
    q.Q1_1 = P00;
    q.Q2_0 = P00+P01+P02+P10+P11+P20;
    q.Q2_1 = P00+P01+P10+P11;
    q.Q2_2 = P00;
    q.Q3_0 = P00+P01+P02+P03+P10+P11+P12+P20+P21+P22+P30;
    q.Q3_1 = P00+P01+P02+P10+P11+P12+P20+P21+P22;
    q.Q3_2 = P00+P01+P02+P10+P11+P12+P20+P21;
    q.Q3_3 = P00;
    q.fz2 = fz*fz;
    return q;
}

// all three K_r with one cosine chain. kx in [0,160).
__device__ __forceinline__ void kval3(const QCol& q, float fy2, int kx, float K[3]){
    float c1 = fcos_rev((float)kx * (1.f/160.f));
    float c2 = 2.f*c1*c1 - 1.f;
    float c3 = 2.f*c1*c2 - c1;
    float s1 = (q.Q1_0 + 2.f*c1*q.Q1_1) * (1.f/7.f);
    float s2 = (q.Q2_0 + 2.f*(c1*q.Q2_1 + c2*q.Q2_2)) * (1.f/33.f);
    float s3 = (q.Q3_0 + 2.f*(c1*q.Q3_1 + c2*q.Q3_2 + c3*q.Q3_3)) * (1.f/123.f);
    float fxw = (float)((kx < 80) ? kx : 160 - kx) * (1.f/160.f);
    float k2 = fxw*fxw + fy2 + q.fz2;
    float D = (1.f/3.f) - ((k2 == 0.f) ? 0.f : q.fz2 * __builtin_amdgcn_rcpf(k2));
    K[0] = (1.f - s1) * D;
    K[1] = (1.f - s2) * D;
    K[2] = (1.f - s3) * D;
}

// ---------------- CG reduction helper ----------------
__device__ __forceinline__ void block_atomic_add(double v, double* target){
    #pragma unroll
    for (int off=32; off>0; off>>=1) v += __shfl_down(v, off, 64);
    __shared__ double sm[4];
    int wv = threadIdx.x >> 6;
    if ((threadIdx.x & 63) == 0) sm[wv] = v;
    __syncthreads();
    if (threadIdx.x == 0) atomicAdd(target, sm[0]+sm[1]+sm[2]+sm[3]);
}

// ======== z-axis kernels: wave-local, barrier-free ========
// Forward passes carry 1/160 each axis; inverse passes are UNscaled.
// PM=0: fft real zin. PM=1: p = r + beta*p (beta=S[3]), store p, fft p.
template<int PM>
__global__ __launch_bounds__(256) void fft_z_first(const float* __restrict__ zin,
    const float* __restrict__ rrv, float* __restrict__ ppv,
    __half2* __restrict__ out, const double* __restrict__ S)
{
    __shared__ float2 ldsC[8*162];
    int tid = threadIdx.x, l = tid & 31, g = tid >> 5;
    int fl = g*162;
    size_t base160 = (size_t)blockIdx.x * 2560 + (size_t)(2*g)*160;
    size_t baseC   = (size_t)blockIdx.x * 1296 + (size_t)g*162;
    float beta = PM ? (float)S[3] : 0.f;
    float2 y[5];
    #pragma unroll
    for (int n1=0;n1<5;n1++){
        int n = n1*32 + l;
        float a, b;
        if (PM){
            a = rrv[base160 + n]       + beta * ppv[base160 + n];
            b = rrv[base160 + 160 + n] + beta * ppv[base160 + 160 + n];
            ppv[base160 + n] = a;
            ppv[base160 + 160 + n] = b;
        } else {
            a = zin[base160 + n];
            b = zin[base160 + 160 + n];
        }
        y[n1] = make_float2(a * SC160, b * SC160);   // fwd 1/160
    }
    linefft<1>(y, l);
    int o5 = 5*br5(l);
    #pragma unroll
    for (int k=0;k<5;k++) ldsC[fl + o5 + k] = y[k];
    #pragma unroll
    for (int t=0;t<6;t++){
        int j = l + 32*t;
        if (j < 162){
            int k = (j < 81) ? j : j - 81;
            float2 Sk = ldsC[fl + k];
            float2 Sm = ldsC[fl + ((160 - k) % 160)];
            float2 o = (j >= 81)
                ? make_float2(0.5f*(Sk.y + Sm.y), -0.5f*(Sk.x - Sm.x))    // B
                : make_float2(0.5f*(Sk.x + Sm.x),  0.5f*(Sk.y - Sm.y));   // A
            out[baseC + j] = f2h(o);
        }
    }
}

// fused: inverse-z (unscaled) -> *(m2w_r/160) -> forward-z
template<bool PRE>
__global__ __launch_bounds__(256) void fft_z_mid3(RPc P, const float* __restrict__ mask,
                                                 const float* __restrict__ wfull)
{
    __shared__ float2 ldsC[8*162];
    int r = blockIdx.y;
    __half2* C = P.C[r];
    int tid = threadIdx.x, l = tid & 31, g = tid >> 5;
    int fl = g*162;
    size_t baseC   = (size_t)blockIdx.x * 1296 + (size_t)g*162;
    size_t base160 = (size_t)blockIdx.x * 2560 + (size_t)(2*g)*160;
    int o5 = 5*br5(l);
    float ma[5], mb[5];
    if (PRE){
        const __half* M = P.M[r];
        #pragma unroll
        for (int k=0;k<5;k++){
            ma[k] = __half2float(M[base160 + o5 + k]) * SC160;
            mb[k] = __half2float(M[base160 + 160 + o5 + k]) * SC160;
        }
    } else {
        #pragma unroll
        for (int k=0;k<5;k++){
            size_t ia = base160 + o5 + k, ib = base160 + 160 + o5 + k;
            float m1 = mask[ia], m2 = mask[ib];
            ma[k] = m1*m1*wfull[ia*3 + r] * SC160;
            mb[k] = m2*m2*wfull[ib*3 + r] * SC160;
        }
    }
    #pragma unroll
    for (int t=0;t<6;t++){
        int j = l + 32*t;
        if (j < 162) ldsC[fl + j] = h2f(C[baseC + j]);
    }
    float2 y[5];
    #pragma unroll
    for (int n1=0;n1<5;n1++){
        int e = n1*32 + l;
        float2 X;
        if (e <= 80){
            float2 A = ldsC[fl + e], B = ldsC[fl + 81 + e];
            X = make_float2(A.x - B.y, A.y + B.x);
        } else {
            int m = 160 - e;
            float2 A = ldsC[fl + m], B = ldsC[fl + 81 + m];
            X = make_float2(A.x + B.y, B.x - A.y);
        }
        y[n1] = X;
    }
    linefft<-1>(y, l);
    #pragma unroll
    for (int k=0;k<5;k++){
        float a = y[k].x * ma[k];
        float b = y[k].y * mb[k];
        ldsC[fl + o5 + k] = make_float2(a, b);
    }
    #pragma unroll
    for (int n1=0;n1<5;n1++) y[n1] = ldsC[fl + n1*32 + l];
    linefft<1>(y, l);
    #pragma unroll
    for (int k=0;k<5;k++) ldsC[fl + o5 + k] = y[k];
    #pragma unroll
    for (int t=0;t<6;t++){
        int j = l + 32*t;
        if (j < 162){
            int k = (j < 81) ? j : j - 81;
            float2 Sk = ldsC[fl + k];
            float2 Sm = ldsC[fl + ((160 - k) % 160)];
            float2 o = (j >= 81)
                ? make_float2(0.5f*(Sk.y + Sm.y), -0.5f*(Sk.x - Sm.x))
                : make_float2(0.5f*(Sk.x + Sm.x),  0.5f*(Sk.y - Sm.y));
            C[baseC + j] = f2h(o);
        }
    }
}

// final inverse-z (unscaled) + epilogue.
// FIN=0: Ap=v, S[1]+=<z,v>. FIN=1: r=b-v -> rr,pp, S[0]+=<r,r>.
template<int FIN>
__global__ __launch_bounds__(256) void fft_z_fin(const __half2* __restrict__ in,
    const float* __restrict__ zsp, float* __restrict__ Ap,
    const float* __restrict__ bb, float* __restrict__ rrv, float* __restrict__ ppv,
    double* __restrict__ S)
{
    __shared__ float2 ldsC[8*162];
    float* ldsF = (float*)ldsC;      // region g: floats [324g, 324g+320)
    int tid = threadIdx.x, l = tid & 31, g = tid >> 5;
    int fl = g*162;
    size_t baseC   = (size_t)blockIdx.x * 1296 + (size_t)g*162;
    size_t base160 = (size_t)blockIdx.x * 2560 + (size_t)(2*g)*160;
    int o5 = 5*br5(l);
    float za[5], zb[5], pa[5], pb[5];
    #pragma unroll
    for (int k=0;k<5;k++){
        za[k] = zsp[base160 + o5 + k];
        zb[k] = zsp[base160 + 160 + o5 + k];
        if (FIN){
            pa[k] = bb[base160 + o5 + k];
            pb[k] = bb[base160 + 160 + o5 + k];
        }
    }
    #pragma unroll
    for (int t=0;t<6;t++){
        int j = l + 32*t;
        if (j < 162) ldsC[fl + j] = h2f(in[baseC + j]);
    }
    float2 y[5];
    #pragma unroll
    for (int n1=0;n1<5;n1++){
        int e = n1*32 + l;
        float2 X;
        if (e <= 80){
            float2 A = ldsC[fl + e], B = ldsC[fl + 81 + e];
            X = make_float2(A.x - B.y, A.y + B.x);
        } else {
            int m = 160 - e;
            float2 A = ldsC[fl + m], B = ldsC[fl + 81 + m];
            X = make_float2(A.x + B.y, B.x - A.y);
        }
        y[n1] = X;
    }
    linefft<-1>(y, l);
    double acc = 0.0;
    int fb = g*324;
    #pragma unroll
    for (int k=0;k<5;k++){
        float va = LAM_F*za[k] + y[k].x;      // inverse unscaled
        float vb = LAM_F*zb[k] + y[k].y;
        if (FIN == 0){
            acc += (double)za[k]*(double)va + (double)zb[k]*(double)vb;
            ldsF[fb + o5 + k] = va;
            ldsF[fb + 160 + o5 + k] = vb;
        } else {
            float ra = pa[k] - va, rb = pb[k] - vb;
            acc += (double)ra*(double)ra + (double)rb*(double)rb;
            ldsF[fb + o5 + k] = ra;
            ldsF[fb + 160 + o5 + k] = rb;
        }
    }
    #pragma unroll
    for (int t=0;t<10;t++){
        int n = l + 32*t;
        float v = ldsF[fb + n];
        if (FIN == 0){
            Ap[base160 + n] = v;
        } else {
            rrv[base160 + n] = v;
            ppv[base160 + n] = v;
        }
    }
    block_atomic_add(acc, FIN ? &S[0] : &S[1]);
}

// ---------------- y-axis sweeps (strided, guarded half-spectrum, W=8) ----------------
// SGN>0 (fwd): scale 1/160 ; SGN<0 (inv): unscaled.
template<int SGN>
__device__ __forceinline__ void ycompute(float2 (*tile)[WZ+1], int tid){
    int l = tid & 31, q = tid >> 5;
    const float SC = (SGN>0) ? SC160 : 1.f;
    float2 y[5];
    #pragma unroll
    for (int n1=0;n1<5;n1++) y[n1] = tile[l + 32*n1][q];
    linefft<SGN>(y, l);
    int o5 = 5*br5(l);
    #pragma unroll
    for (int k=0;k<5;k++) tile[o5+k][q] = cscale(y[k], SC);
}

// b = zchunk*160 + ix  (zb-outer so line-sharing blocks b, b+160 share an XCD)
template<int SGN>
__global__ __launch_bounds__(256) void fft_y1(__half2* __restrict__ data)
{
    __shared__ float2 tile[NN][WZ+1];
    int b = blockIdx.x;
    int ix = b % 160, zb = (b / 160) * WZ;
    size_t tbase = (size_t)ix*XS + zb;
    int tid = threadIdx.x;
    for (int i = tid; i < NN*WZ; i += 256){
        int row = i >> 3, zi = i & 7;
        tile[row][zi] = (zb + zi < KP) ? h2f(data[tbase + (size_t)row*KP + zi]) : make_float2(0.f,0.f);
    }
    __syncthreads();
    ycompute<SGN>(tile, tid);
    __syncthreads();
    for (int i = tid; i < NN*WZ; i += 256){
        int row = i >> 3, zi = i & 7;
        if (zb + zi < KP) data[tbase + (size_t)row*KP + zi] = f2h(tile[row][zi]);
    }
}

template<int SGN>
__global__ __launch_bounds__(256) void fft_y3(RPc P)
{
    __shared__ float2 tile[NN][WZ+1];
    __half2* data = P.C[blockIdx.y];
    int b = blockIdx.x;
    int ix = b % 160, zb = (b / 160) * WZ;
    size_t tbase = (size_t)ix*XS + zb;
    int tid = threadIdx.x;
    for (int i = tid; i < NN*WZ; i += 256){
        int row = i >> 3, zi = i & 7;
        tile[row][zi] = (zb + zi < KP) ? h2f(data[tbase + (size_t)row*KP + zi]) : make_float2(0.f,0.f);
    }
    __syncthreads();
    ycompute<SGN>(tile, tid);
    __syncthreads();
    for (int i = tid; i < NN*WZ; i += 256){
        int row = i >> 3, zi = i & 7;
        if (zb + zi < KP) data[tbase + (size_t)row*KP + zi] = f2h(tile[row][zi]);
    }
}

// ---------------- x-axis kernels with analytic K (W=4, 128 threads) ----------------
// spread: one block per (iy, 4-col zb chunk). Own-column loads, shared fwd-x
// FFT once, BATCHED-BY-3 inverse FFT (stage-interleaved shuffle ILP), one
// barrier, 3 coop stores.
__global__ __launch_bounds__(128) void fft_xK(RPc P, const __half2* __restrict__ in)
{
    __shared__ __half2 t0[NN][XW+1], t1[NN][XW+1], t2[NN][XW+1];
    int b = blockIdx.x;
    int iy = b % 160, zb = (b / 160) * XW;
    size_t tbase = (size_t)iy*KP + zb;
    int tid = threadIdx.x, l = tid & 31, q = tid >> 5;   // q in [0,4)
    bool okc = (zb + q < KP);
    float2 spec[5];
    #pragma unroll
    for (int n1=0;n1<5;n1++){
        int row = n1*32 + l;
        spec[n1] = okc ? h2f(in[tbase + (size_t)row*XS + q]) : make_float2(0.f,0.f);
    }
    float fy = (float)((iy < 80) ? iy : iy - 160) * (1.f/160.f);
    float fy2 = fy*fy;
    float cy1 = fcos_rev(fy);
    float cy2 = 2.f*cy1*cy1 - 1.f;
    float cy3 = 2.f*cy1*cy2 - cy1;
    QCol qc = make_qcol(1.f, 2.f*cy1, 2.f*cy2, 2.f*cy3, zb + q);
    int o5 = 5*br5(l);
    linefft<1>(spec, l);
    float K3[5][3];
    #pragma unroll
    for (int k=0;k<5;k++) kval3(qc, fy2, o5+k, K3[k]);
    float2 a[3][5];
    #pragma unroll
    for (int j=0;j<3;j++)
        for (int k=0;k<5;k++) a[j][k] = cscale(spec[k], K3[k][j] * SC160);
    ilinefft_perm_b3(a, l);
    #pragma unroll
    for (int n1=0;n1<5;n1++){
        t0[n1*32 + l][q] = f2h(a[0][n1]);
        t1[n1*32 + l][q] = f2h(a[1][n1]);
        t2[n1*32 + l][q] = f2h(a[2][n1]);
    }
    __syncthreads();
    {
        __half2* Cr = P.C[0];
        for (int i = tid; i < NN*XW; i += 128){
            int row = i >> 2, zi = i & 3;
            if (zb + zi < KP) Cr[tbase + (size_t)row*XS + zi] = t0[row][zi];
        }
    }
    {
        __half2* Cr = P.C[1];
        for (int i = tid; i < NN*XW; i += 128){
            int row = i >> 2, zi = i & 3;
            if (zb + zi < KP) Cr[tbase + (size_t)row*XS + zi] = t1[row][zi];
        }
    }
    {
        __half2* Cr = P.C[2];
        for (int i = tid; i < NN*XW; i += 128){
            int row = i >> 2, zi = i & 3;
            if (zb + zi < KP) Cr[tbase + (size_t)row*XS + zi] = t2[row][zi];
        }
    }
}

// gather: CF = invx( sum_r (K_r/160) * fwdx(C_r) ). W=4, 128 threads.
// Hoisted own-column loads, BATCHED-BY-3 forward FFT, single inverse.
__global__ __launch_bounds__(128) void fft_xgather(RPc P, __half2* __restrict__ out)
{
    __shared__ __half2 tile[NN][XW+1];
    int b = blockIdx.x;
    int iy = b % 160, zb = (b / 160) * XW;
    size_t tbase = (size_t)iy*KP + zb;
    int tid = threadIdx.x, l = tid & 31, q = tid >> 5;
    bool okc = (zb + q < KP);
    float2 v[3][5];
    #pragma unroll
    for (int n1=0;n1<5;n1++){
        size_t a = tbase + (size_t)(n1*32 + l)*XS + q;
        v[0][n1] = okc ? h2f(P.C[0][a]) : make_float2(0.f,0.f);
        v[1][n1] = okc ? h2f(P.C[1][a]) : make_float2(0.f,0.f);
        v[2][n1] = okc ? h2f(P.C[2][a]) : make_float2(0.f,0.f);
    }
    float fy = (float)((iy < 80) ? iy : iy - 160) * (1.f/160.f);
    float fy2 = fy*fy;
    float cy1 = fcos_rev(fy);
    float cy2 = 2.f*cy1*cy1 - 1.f;
    float cy3 = 2.f*cy1*cy2 - cy1;
    QCol qc = make_qcol(1.f, 2.f*cy1, 2.f*cy2, 2.f*cy3, zb + q);
    int o5 = 5*br5(l);
    float K3[5][3];
    #pragma unroll
    for (int k=0;k<5;k++) kval3(qc, fy2, o5+k, K3[k]);
    linefft_b3<1>(v, l);
    float2 acc[5];
    #pragma unroll
    for (int k=0;k<5;k++){
        acc[k] = cscale(v[0][k], K3[k][0] * SC160);
        acc[k] = cadd(acc[k], cscale(v[1][k], K3[k][1] * SC160));
        acc[k] = cadd(acc[k], cscale(v[2][k], K3[k][2] * SC160));
    }
    ilinefft_perm(acc, l);
    #pragma unroll
    for (int n1=0;n1<5;n1++) tile[n1*32 + l][q] = f2h(acc[n1]);
    __syncthreads();
    for (int i = tid; i < NN*XW; i += 128){
        int row = i >> 2, zi = i & 3;
        if (zb + zi < KP) out[tbase + (size_t)row*XS + zi] = tile[row][zi];
    }
}

// ---------------- setup / CG vector ops ----------------
__global__ __launch_bounds__(256) void m2w_kernel(const float* __restrict__ mask,
        const float* __restrict__ w, __half* __restrict__ M0,
        __half* __restrict__ M1, __half* __restrict__ M2)
{
    int i = blockIdx.x*256 + threadIdx.x;
    float m = mask[i]; float mm = m*m;
    M0[i] = __float2half(mm * w[3*(size_t)i+0]);
    M1[i] = __float2half(mm * w[3*(size_t)i+1]);
    M2[i] = __float2half(mm * w[3*(size_t)i+2]);
}

__global__ __launch_bounds__(256) void copy_kernel(const float* __restrict__ a, float* __restrict__ b){
    int i = blockIdx.x*256 + threadIdx.x;
    b[i] = a[i];
}

#define GSTRIDE (2048*256)
__global__ __launch_bounds__(256) void upd1_kernel(float* __restrict__ x, float* __restrict__ r,
        const float* __restrict__ p, const float* __restrict__ Ap, double* s)
{
    float alpha = (float)(s[0] / (s[1] + 1e-12));
    double acc = 0.0;
    for (int i = blockIdx.x*256 + threadIdx.x; i < N3; i += GSTRIDE){
        x[i] += alpha * p[i];
        float rn = r[i] - alpha * Ap[i];
        r[i] = rn;
        acc += (double)rn * (double)rn;
    }
    block_atomic_add(acc, &s[2]);
}
__global__ void advance_kernel(double* s){
    if (threadIdx.x == 0){
        s[3] = s[2] / (s[0] + 1e-12);   // beta
        s[0] = s[2]; s[1] = 0.0; s[2] = 0.0;
    }
}
__global__ void zero_kernel(double* s){
    if (threadIdx.x < 4) s[threadIdx.x] = 0.0;
}

// ---------------- host orchestration ----------------
extern "C" void kernel_launch(void* const* d_in, const int* in_sizes, int n_in,
                              void* d_out, int out_size, void* d_ws, size_t ws_size,
                              hipStream_t stream)
{
    (void)in_sizes; (void)n_in; (void)out_size;
    const float* w    = (const float*)d_in[0];   // [N3*3], R fastest
    const float* x2   = (const float*)d_in[1];   // [N3]
    const float* mask = (const float*)d_in[2];   // [N3]
    const float* bb   = (const float*)d_in[3];   // [N3]
    float* x = (float*)d_out;
    char* ws = (char*)d_ws;

    size_t off = 0;
    auto alloc = [&](size_t bytes)->void*{
        void* pp = ws + off;
        off += (bytes + 255) & ~(size_t)255;
        return pp;
    };
    const size_t CB = (size_t)NLINES * KP * sizeof(__half2);   // 8.3 MB
    __half2* CF = (__half2*)alloc(CB);
    __half2* C0 = (__half2*)alloc(CB);
    __half2* C1 = (__half2*)alloc(CB);
    __half2* C2 = (__half2*)alloc(CB);
    float*  rr = (float*) alloc((size_t)N3*4);
    float*  pp = (float*) alloc((size_t)N3*4);
    float*  Ap = (float*) alloc((size_t)N3*4);
    double* S  = (double*)alloc(64);
    bool PRE = (ws_size >= off + 3*(((size_t)N3*2 + 255) & ~(size_t)255));
    __half *M0=nullptr, *M1=nullptr, *M2=nullptr;
    if (PRE){
        M0 = (__half*)alloc((size_t)N3*2);
        M1 = (__half*)alloc((size_t)N3*2);
        M2 = (__half*)alloc((size_t)N3*2);
    }
    RPc P;
    P.C[0]=C0; P.C[1]=C1; P.C[2]=C2;
    P.M[0]=M0; P.M[1]=M1; P.M[2]=M2;

    zero_kernel<<<1, 64, 0, stream>>>(S);
    if (PRE) m2w_kernel<<<16000, 256, 0, stream>>>(mask, w, M0, M1, M2);
    copy_kernel<<<16000, 256, 0, stream>>>(x2, x);

    const int GY = NBZ * 160;    // 1760 (y kernels, W=8)
    const int GX4 = NBX4 * 160;  // 3360 (x kernels, W=4)
    // PM: 0 = plain fft of z; 1 = fused p-update. FIN: 1 = initial residual, 0 = CG iter.
    auto applyM = [&](const float* z, int FIN, int PM){
        if (PM) fft_z_first<1><<<1600, 256, 0, stream>>>(z, rr, pp, CF, S);
        else    fft_z_first<0><<<1600, 256, 0, stream>>>(z, rr, pp, CF, S);
        fft_y1<1><<<GY, 256, 0, stream>>>(CF);
        fft_xK<<<GX4, 128, 0, stream>>>(P, CF);
        fft_y3<-1><<<dim3(GY,3), 256, 0, stream>>>(P);
        if (PRE) fft_z_mid3<true ><<<dim3(1600,3), 256, 0, stream>>>(P, mask, w);
        else     fft_z_mid3<false><<<dim3(1600,3), 256, 0, stream>>>(P, mask, w);
        fft_y3<1><<<dim3(GY,3), 256, 0, stream>>>(P);
        fft_xgather<<<GX4, 128, 0, stream>>>(P, CF);
        fft_y1<-1><<<GY, 256, 0, stream>>>(CF);
        if (FIN) fft_z_fin<1><<<1600, 256, 0, stream>>>(CF, x, Ap, bb, rr, pp, S);
        else     fft_z_fin<0><<<1600, 256, 0, stream>>>(CF, pp, Ap, bb, rr, pp, S);
    };

    // r = b - M(x2); p = r; rs = <r,r>
    applyM(x, 1, 0);

    for (int it = 0; it < 10; it++){
        applyM(pp, 0, (it == 0) ? 0 : 1);          // Ap = M(p), S[1] = <p,Ap>
        upd1_kernel<<<2048, 256, 0, stream>>>(x, rr, pp, Ap, S);
        if (it < 9) advance_kernel<<<1, 64, 0, stream>>>(S);
    }
}